// Round 23
// baseline (257.014 us; speedup 1.0000x reference)
//
#include <hip/hip_runtime.h>
#include <hip/hip_fp16.h>

#define S_TOK 8192
#define DDIM  1024
#define HDIM  4096
#define NEXP  8
#define CAP   1024

typedef __attribute__((ext_vector_type(8))) _Float16 half8;
typedef __attribute__((ext_vector_type(4))) float f32x4;
typedef __attribute__((ext_vector_type(16))) float f32x16;

__device__ __forceinline__ void load_lds16(const _Float16* g, _Float16* l) {
  __builtin_amdgcn_global_load_lds(
      (const __attribute__((address_space(1))) unsigned int*)g,
      (__attribute__((address_space(3))) unsigned int*)l, 16, 0, 0);
}

// ---------------- fused prep: gating (blocks 0..2047) + w1 transpose (2048..) ----------------
__global__ __launch_bounds__(256) void prep_fused(const float* __restrict__ x,
                                                  const float* __restrict__ wg,
                                                  int* __restrict__ eidx,
                                                  float* __restrict__ gtok,
                                                  const float* __restrict__ w1,
                                                  _Float16* __restrict__ wt) {
  if (blockIdx.x < S_TOK / 4) {
    const int s = blockIdx.x * 4 + (threadIdx.x >> 6);
    const int lane = threadIdx.x & 63;
    const float* xr = x + (size_t)s * DDIM;
    float acc[NEXP];
#pragma unroll
    for (int e = 0; e < NEXP; ++e) acc[e] = 0.f;
    for (int d = lane; d < DDIM; d += 64) {
      float xv = xr[d];
      const float4* wrow = (const float4*)(wg + (size_t)d * NEXP);
      float4 w0 = wrow[0], w1v = wrow[1];
      acc[0] += xv * w0.x;  acc[1] += xv * w0.y;
      acc[2] += xv * w0.z;  acc[3] += xv * w0.w;
      acc[4] += xv * w1v.x; acc[5] += xv * w1v.y;
      acc[6] += xv * w1v.z; acc[7] += xv * w1v.w;
    }
#pragma unroll
    for (int off = 32; off > 0; off >>= 1) {
#pragma unroll
      for (int e = 0; e < NEXP; ++e) acc[e] += __shfl_down(acc[e], off);
    }
    if (lane == 0) {
      int best = 0; float bv = acc[0];
#pragma unroll
      for (int e = 1; e < NEXP; ++e) if (acc[e] > bv) { bv = acc[e]; best = e; }
      float sum = 0.f;
#pragma unroll
      for (int e = 0; e < NEXP; ++e) sum += expf(acc[e] - bv);
      eidx[s] = best;
      gtok[s] = 1.f / sum;   // exp(best - max) == 1
    }
  } else {
    __shared__ float tile[64][68];
    const int bid = blockIdx.x - S_TOK / 4;
    const int bx = bid & 63;            // HDIM/64 = 64
    const int by = (bid >> 6) & 15;     // DDIM/64 = 16
    const int bz = bid >> 10;           // NEXP = 8
    const size_t mat = (size_t)DDIM * HDIM;
    const float* ip = w1 + (size_t)bz * mat;
    _Float16* op = wt + (size_t)bz * mat;
    const int r0 = by * 64, c0 = bx * 64;
    {
      const int rl = threadIdx.x >> 2;
      const int cb = (threadIdx.x & 3) * 16;
      const float* src = ip + (size_t)(r0 + rl) * HDIM + c0 + cb;
#pragma unroll
      for (int k = 0; k < 4; ++k) {
        float4 v = *(const float4*)(src + 4 * k);
        tile[rl][cb + 4 * k + 0] = v.x;
        tile[rl][cb + 4 * k + 1] = v.y;
        tile[rl][cb + 4 * k + 2] = v.z;
        tile[rl][cb + 4 * k + 3] = v.w;
      }
    }
    __syncthreads();
    const int cl = threadIdx.x >> 3;
    const int rch = (threadIdx.x & 7) * 8;
#pragma unroll
    for (int pass = 0; pass < 2; ++pass) {
      int cc = cl + pass * 32;
      half8 v;
#pragma unroll
      for (int i = 0; i < 8; ++i) v[i] = (_Float16)tile[rch + i][cc];
      *(half8*)(op + (size_t)(c0 + cc) * DDIM + r0 + rch) = v;
    }
  }
}

// ---------------- scanA: per-64-token expert counts + s2t/rgate init ----------------
// 128 blocks x 64 lanes tile the 8192 slots exactly; init here is strictly
// ordered before scanBC's slot writes (separate launch).
__global__ __launch_bounds__(64) void scanA(const int* __restrict__ eidx,
                                            int* __restrict__ cnt,
                                            int* __restrict__ s2t,
                                            float* __restrict__ rgate) {
  const int blk = blockIdx.x;
  const int lane = threadIdx.x;
  const int slot = blk * 64 + lane;
  s2t[slot] = -1;
  rgate[slot] = 0.f;
  int e = eidx[slot];
#pragma unroll
  for (int w = 0; w < NEXP; ++w) {
    unsigned long long m = __ballot(e == w);
    if (lane == 0) cnt[blk * NEXP + w] = __popcll(m);
  }
}

// ---------------- scanBC: per-block prefix (recomputed) + ballot scatter ----------------
// Each block computes its own 8 expert offsets by looping cnt[0..blk) (L2-hot,
// <=127 reads/lane), broadcasts via shfl, then scatters as before. Removes the
// separate 1-block scanB launch + its serialization bubble.
__global__ __launch_bounds__(64) void scanBC(const int* __restrict__ cnt,
                                             const int* __restrict__ eidx,
                                             const float* __restrict__ gtok,
                                             int* __restrict__ s2t,
                                             float* __restrict__ rgate,
                                             int* __restrict__ keepf) {
  const int blk = blockIdx.x;
  const int lane = threadIdx.x;
  int off_w = 0;
  if (lane < NEXP) {
    for (int b = 0; b < blk; ++b) off_w += cnt[b * NEXP + lane];
  }
  const int tok = blk * 64 + lane;
  int e = eidx[tok];
  float g = gtok[tok];
  const unsigned long long below = (1ull << lane) - 1ull;
#pragma unroll
  for (int w = 0; w < NEXP; ++w) {
    int base = __shfl(off_w, w);
    unsigned long long m = __ballot(e == w);
    if (e == w) {
      int slot = base + __popcll(m & below);
      if (slot < CAP) { s2t[w * CAP + slot] = tok; rgate[w * CAP + slot] = g; }
      keepf[tok] = (slot < CAP) ? 1 : 0;   // every token written exactly once
    }
  }
}

// ---------------- fused dispatch (blocks 0..8191) + zero-dropped (8192..) ----------------
__global__ __launch_bounds__(128) void dispatch_zero(const float* __restrict__ x,
                                                     const int* __restrict__ s2t,
                                                     _Float16* __restrict__ disp,
                                                     const int* __restrict__ keepf,
                                                     float* __restrict__ y) {
  if (blockIdx.x < NEXP * CAP) {
    const int row = blockIdx.x;
    const int t = threadIdx.x;
    const int token = s2t[row];
    half8 v;
    if (token >= 0) {
      const float4* xr = (const float4*)(x + (size_t)token * DDIM);
      float4 a = xr[2 * t], b = xr[2 * t + 1];
      v[0] = (_Float16)a.x; v[1] = (_Float16)a.y; v[2] = (_Float16)a.z; v[3] = (_Float16)a.w;
      v[4] = (_Float16)b.x; v[5] = (_Float16)b.y; v[6] = (_Float16)b.z; v[7] = (_Float16)b.w;
    } else {
#pragma unroll
      for (int i = 0; i < 8; ++i) v[i] = (_Float16)0.f;
    }
    *(half8*)(disp + (size_t)row * DDIM + t * 8) = v;
  } else {
    const int tok = (blockIdx.x - NEXP * CAP) * 2 + (threadIdx.x >> 6);
    if (keepf[tok]) return;
    const int lane = threadIdx.x & 63;
    float4* yr = (float4*)(y + (size_t)tok * DDIM);
#pragma unroll
    for (int i = 0; i < 4; ++i) yr[lane + i * 64] = {0.f, 0.f, 0.f, 0.f};
  }
}

// ---------------- GEMM1: m201 8-phase template (r8/r16-proven, ~93 us) ----------------
template <int KDIM, int NDIM, int SPLITK, bool FIRST>
__global__ __launch_bounds__(512, 2) void ffn_gemm_m(const _Float16* __restrict__ A_set,
                                                     const _Float16* __restrict__ B_set,
                                                     _Float16* __restrict__ Hout,
                                                     float* __restrict__ Y,
                                                     const int* __restrict__ s2t,
                                                     const float* __restrict__ rgate) {
  __shared__ __align__(16) _Float16 As[4 * 8192];   // [d*2+h][128][64]
  __shared__ __align__(16) _Float16 Bs[4 * 8192];
  constexpr int TILES = 4 * (NDIM / 256);
  constexpr int PER_E = TILES * SPLITK;
  constexpr int NTSEG = KDIM / 64 / SPLITK;
  constexpr int NI = NTSEG / 2;
  const int wg = blockIdx.x;
  const int swz = (wg & 7) * PER_E + (wg >> 3);   // bijective; xcd == expert
  const int z = swz / PER_E;
  const int s2 = swz % PER_E;
  const int tile = s2 % TILES;
  const int kseg = s2 / TILES;
  const int m0 = (tile & 3) * 256;
  const int n0 = (tile >> 2) * 256;
  const int kt0 = kseg * NTSEG;

  const int tid = threadIdx.x;
  const _Float16* Ae = A_set + (size_t)z * 1024 * KDIM;
  const _Float16* Be = B_set + (size_t)z * (size_t)NDIM * KDIM;

  const int sr0 = tid >> 3;
  const int sc0 = tid & 7;
  auto STG = [&](const _Float16* gbase, _Float16* lbase, int rowbase, int kt) {
#pragma unroll
    for (int j = 0; j < 2; ++j) {
      int r = j * 64 + sr0;
      load_lds16(gbase + (size_t)(rowbase + r) * KDIM + kt * 64 + ((sc0 ^ (r & 7)) << 3),
                 lbase + j * 4096 + tid * 8);
    }
  };

  const int lane = tid & 63, wid = tid >> 6;
  const int fr = lane & 15, fq = lane >> 4;
  const int war = (wid >> 2) * 64;
  const int wbr = (wid & 3) * 32;
  int offA[4][2], offB[2][2];
#pragma unroll
  for (int m = 0; m < 4; ++m)
#pragma unroll
    for (int ks = 0; ks < 2; ++ks) {
      int r = war + m * 16 + fr, c = ks * 4 + fq;
      offA[m][ks] = r * 64 + ((c ^ (r & 7)) << 3);
    }
#pragma unroll
  for (int n = 0; n < 2; ++n)
#pragma unroll
    for (int ks = 0; ks < 2; ++ks) {
      int r = wbr + n * 16 + fr, c = ks * 4 + fq;
      offB[n][ks] = r * 64 + ((c ^ (r & 7)) << 3);
    }

  f32x4 acc[4][4][2];
#pragma unroll
  for (int q = 0; q < 4; ++q)
#pragma unroll
    for (int m = 0; m < 4; ++m)
#pragma unroll
      for (int n = 0; n < 2; ++n) acc[q][m][n] = {0.f, 0.f, 0.f, 0.f};

#define BAR __builtin_amdgcn_s_barrier()
#define PUBFENCE __builtin_amdgcn_sched_barrier(0)
#define RDA(KK, MH) { _Pragma("unroll") for (int m = 0; m < 4; ++m) { \
      af[m][0] = *(const half8*)(As + ((KK) * 2 + (MH)) * 8192 + offA[m][0]); \
      af[m][1] = *(const half8*)(As + ((KK) * 2 + (MH)) * 8192 + offA[m][1]); } }
#define RDB(KK, NH, BF) { _Pragma("unroll") for (int n = 0; n < 2; ++n) { \
      BF[n][0] = *(const half8*)(Bs + ((KK) * 2 + (NH)) * 8192 + offB[n][0]); \
      BF[n][1] = *(const half8*)(Bs + ((KK) * 2 + (NH)) * 8192 + offB[n][1]); } }
#define MM16(Q, BF) { __builtin_amdgcn_s_setprio(1); \
    _Pragma("unroll") for (int ks = 0; ks < 2; ++ks) \
    _Pragma("unroll") for (int m = 0; m < 4; ++m) \
    _Pragma("unroll") for (int n = 0; n < 2; ++n) \
      acc[Q][m][n] = __builtin_amdgcn_mfma_f32_16x16x32_f16(af[m][ks], BF[n][ks], acc[Q][m][n], 0, 0, 0); \
    __builtin_amdgcn_s_setprio(0); }

  STG(Ae, As + 0 * 8192, m0 + 0,   kt0);
  STG(Be, Bs + 0 * 8192, n0 + 0,   kt0);
  STG(Ae, As + 1 * 8192, m0 + 128, kt0);
  STG(Be, Bs + 1 * 8192, n0 + 128, kt0);
  STG(Ae, As + 2 * 8192, m0 + 0,   kt0 + 1);
  STG(Be, Bs + 2 * 8192, n0 + 0,   kt0 + 1);
  asm volatile("s_waitcnt vmcnt(4)" ::: "memory");
  PUBFENCE;
  BAR;

#pragma unroll 1
  for (int i = 0; i < NI; ++i) {
    const int ka = kt0 + 2 * i;
    const bool more = (i + 1 < NI);
    half8 af[4][2], bfA[2][2], bfB[2][2];
    RDA(0, 0); RDB(0, 0, bfA);
    STG(Ae, As + 3 * 8192, m0 + 128, ka + 1);
    BAR; MM16(0, bfA); BAR;
    RDB(0, 1, bfB);
    STG(Be, Bs + 3 * 8192, n0 + 128, ka + 1);
    BAR; MM16(1, bfB); BAR;
    RDA(0, 1);
    if (more) STG(Ae, As + 0 * 8192, m0 + 0, ka + 2);
    BAR; MM16(2, bfA); BAR;
    if (more) {
      STG(Be, Bs + 0 * 8192, n0 + 0, ka + 2);
      asm volatile("s_waitcnt vmcnt(4)" ::: "memory");
    } else {
      asm volatile("s_waitcnt vmcnt(0)" ::: "memory");
    }
    PUBFENCE;
    BAR; MM16(3, bfB); BAR;
    RDA(1, 0); RDB(1, 0, bfA);
    if (more) STG(Ae, As + 1 * 8192, m0 + 128, ka + 2);
    BAR; MM16(0, bfA); BAR;
    RDB(1, 1, bfB);
    if (more) STG(Be, Bs + 1 * 8192, n0 + 128, ka + 2);
    BAR; MM16(1, bfB); BAR;
    RDA(1, 1);
    if (more) STG(Ae, As + 2 * 8192, m0 + 0, ka + 3);
    BAR; MM16(2, bfA); BAR;
    if (more) {
      STG(Be, Bs + 2 * 8192, n0 + 0, ka + 3);
      asm volatile("s_waitcnt vmcnt(4)" ::: "memory");
      PUBFENCE;
    }
    BAR; MM16(3, bfB); BAR;
  }
#undef MM16
#undef RDB
#undef RDA
#undef PUBFENCE
#undef BAR

#pragma unroll
  for (int q = 0; q < 4; ++q) {
    const int mh = q >> 1, nh = q & 1;
#pragma unroll
    for (int m = 0; m < 4; ++m) {
      const int rowb = m0 + mh * 128 + war + m * 16 + fq * 4;
      const int colb = n0 + nh * 128 + wbr + fr;
      if (FIRST) {
#pragma unroll
        for (int j = 0; j < 4; ++j) {
          size_t row = (size_t)z * 1024 + rowb + j;
#pragma unroll
          for (int n = 0; n < 2; ++n)
            Hout[row * (size_t)NDIM + colb + n * 16] = (_Float16)fmaxf(acc[q][m][n][j], 0.f);
        }
      } else {
        const int srow = z * CAP + rowb;
#pragma unroll
        for (int j = 0; j < 4; ++j) {
          int token = s2t[srow + j];
          if (token < 0) continue;
          float g = rgate[srow + j];
#pragma unroll
          for (int n = 0; n < 2; ++n) {
            if (SPLITK > 1)
              atomicAdd(&Y[(size_t)token * DDIM + colb + n * 16], acc[q][m][n][j] * g);
            else
              Y[(size_t)token * DDIM + colb + n * 16] = acc[q][m][n][j] * g;
          }
        }
      }
    }
  }
}

// ---------------- GEMM2 "fused-B v5.2" (r21-proven, ~117 us) ----------------
template <int KDIM, int NDIM>
__global__ __launch_bounds__(512, 1) void ffn_gemm_f2(const _Float16* __restrict__ A_set,
                                                      const float* __restrict__ B_set,
                                                      float* __restrict__ Y,
                                                      const int* __restrict__ s2t,
                                                      const float* __restrict__ rgate) {
  __shared__ __align__(16) _Float16 As[2 * 16384];  // [buf][256 rows][64 k]
  __shared__ __align__(16) _Float16 Bs[2 * 8192];   // [buf][128 n][64 k]
  constexpr int NT = KDIM / 64;
  constexpr int TILES = (NDIM / 128) * 4;
  const int wg = blockIdx.x;
  const int swz = (wg & 7) * TILES + (wg >> 3);
  const int z = swz / TILES;
  const int s2 = swz % TILES;
  const int xx = s2 >> 2;
  const int yy = s2 & 3;
  const int m0 = yy * 256, n0 = xx * 128;

  const int tid = threadIdx.x;
  const _Float16* Ae = A_set + (size_t)z * 1024 * KDIM;
  const float* Be = B_set + (size_t)z * (size_t)KDIM * NDIM;

  const int sr = tid >> 3;
  const int sc = tid & 7;
  auto STAGE_A = [&](int buf, int kt) {
#pragma unroll
    for (int j = 0; j < 4; ++j) {
      int r = j * 64 + sr;
      load_lds16(Ae + (size_t)(m0 + r) * KDIM + kt * 64 + ((sc ^ (r & 7)) << 3),
                 As + buf * 16384 + j * 4096 + tid * 8);
    }
  };

  const int bq = tid & 31;
  const int bkb = ((tid >> 5) & 7) * 8;
  auto LOAD_B = [&](float4* br, int kt) {
#pragma unroll
    for (int i = 0; i < 8; ++i)
      br[i] = *(const float4*)(Be + (size_t)(kt * 64 + bkb + i) * NDIM + n0 + 4 * bq);
  };
  auto WRITE_B = [&](const float4* br, int buf) {
    _Float16* Bb = Bs + buf * 8192;
#pragma unroll
    for (int w = 0; w < 4; ++w) {
      int n = 4 * bq + w;
      half8 h;
#pragma unroll
      for (int i = 0; i < 8; ++i) h[i] = (_Float16)br[i][w];
      int c = (bkb >> 3) ^ (((n >> 2) ^ n) & 7);
      *(half8*)(Bb + n * 64 + c * 8) = h;
    }
  };

  const int lane = tid & 63, wid = tid >> 6;
  const bool bstage = (wid < 4);
  const int wr = (wid >> 1) * 64;
  const int wc = (wid & 1) * 64;
  const int r32 = lane & 31;
  const int khalf = lane >> 5;
  int offA[2][4], offB[2][4];
#pragma unroll
  for (int t2 = 0; t2 < 2; ++t2)
#pragma unroll
    for (int kf = 0; kf < 4; ++kf) {
      int ra = wr + t2 * 32 + r32, c = kf * 2 + khalf;
      offA[t2][kf] = ra * 64 + ((c ^ (ra & 7)) << 3);
      int nb = wc + t2 * 32 + r32;
      offB[t2][kf] = nb * 64 + ((c ^ (((nb >> 2) ^ nb) & 7)) << 3);
    }

  f32x16 acc[2][2];
#pragma unroll
  for (int m = 0; m < 2; ++m)
#pragma unroll
    for (int n = 0; n < 2; ++n)
#pragma unroll
      for (int j = 0; j < 16; ++j) acc[m][n][j] = 0.f;

  auto COMPUTE = [&](int buf) {
    const _Float16* Ab = As + buf * 16384;
    const _Float16* Bb = Bs + buf * 8192;
    __builtin_amdgcn_s_setprio(1);
#pragma unroll
    for (int kf = 0; kf < 4; ++kf) {
      half8 a0 = *(const half8*)(Ab + offA[0][kf]);
      half8 a1 = *(const half8*)(Ab + offA[1][kf]);
      half8 b0 = *(const half8*)(Bb + offB[0][kf]);
      half8 b1 = *(const half8*)(Bb + offB[1][kf]);
      acc[0][0] = __builtin_amdgcn_mfma_f32_32x32x16_f16(a0, b0, acc[0][0], 0, 0, 0);
      acc[0][1] = __builtin_amdgcn_mfma_f32_32x32x16_f16(a0, b1, acc[0][1], 0, 0, 0);
      acc[1][0] = __builtin_amdgcn_mfma_f32_32x32x16_f16(a1, b0, acc[1][0], 0, 0, 0);
      acc[1][1] = __builtin_amdgcn_mfma_f32_32x32x16_f16(a1, b1, acc[1][1], 0, 0, 0);
    }
    __builtin_amdgcn_s_setprio(0);
  };

#define BARRIER8 do { \
    if (bstage) asm volatile("s_waitcnt vmcnt(8) lgkmcnt(0)" ::: "memory"); \
    else        asm volatile("s_waitcnt vmcnt(0) lgkmcnt(0)" ::: "memory"); \
    __builtin_amdgcn_sched_barrier(0); \
    __builtin_amdgcn_s_barrier(); \
    __builtin_amdgcn_sched_barrier(0); } while (0)

  float4 bregA[8], bregB[8];
  if (bstage) LOAD_B(bregA, 0);
  STAGE_A(0, 0);
  if (bstage) {
    WRITE_B(bregA, 0);
    LOAD_B(bregB, 1 & (NT - 1));
  }
  BARRIER8;

#pragma unroll 1
  for (int i = 0; i < NT; i += 2) {
    STAGE_A(1, (i + 1) & (NT - 1));
    if (bstage) {
      LOAD_B(bregA, (i + 2) & (NT - 1));
      WRITE_B(bregB, 1);          // cvt+ds_write overlap the MFMA cluster below
    }
    COMPUTE(0);
    BARRIER8;
    if (i + 2 < NT) STAGE_A(0, (i + 2) & (NT - 1));
    if (bstage) {
      LOAD_B(bregB, (i + 3) & (NT - 1));
      if (i + 2 < NT) WRITE_B(bregA, 0);
    }
    COMPUTE(1);
    BARRIER8;
  }
#undef BARRIER8

#pragma unroll
  for (int mt = 0; mt < 2; ++mt) {
#pragma unroll
    for (int nt = 0; nt < 2; ++nt) {
      const int gcol = n0 + wc + nt * 32 + r32;
#pragma unroll
      for (int reg = 0; reg < 16; ++reg) {
        const int rowf = (reg & 3) + 8 * (reg >> 2) + 4 * khalf;
        const int grow = m0 + wr + mt * 32 + rowf;
        int token = s2t[z * CAP + grow];
        if (token >= 0) {
          float g = rgate[z * CAP + grow];
          Y[(size_t)token * DDIM + gcol] = acc[mt][nt][reg] * g;
        }
      }
    }
  }
}

extern "C" void kernel_launch(void* const* d_in, const int* in_sizes, int n_in,
                              void* d_out, int out_size, void* d_ws, size_t ws_size,
                              hipStream_t stream) {
  const float* x  = (const float*)d_in[0];
  const float* wg = (const float*)d_in[1];
  const float* w1 = (const float*)d_in[2];
  const float* w2 = (const float*)d_in[3];
  float* y = (float*)d_out;

  char* ws = (char*)d_ws;
  int*   eidx  = (int*)(ws);                 // 32 KB
  float* gtok  = (float*)(ws + 32768);       // 32 KB
  int*   s2t   = (int*)(ws + 65536);         // 32 KB
  float* rgate = (float*)(ws + 98304);       // 32 KB
  int*   cnt   = (int*)(ws + 131072);        // 4 KB
  int*   keepf = (int*)(ws + 139264);        // 32 KB
  _Float16* disp = (_Float16*)(ws + 180224); // 16 MB
  char* big = ws + 180224 + (size_t)NEXP * CAP * DDIM * 2;
  _Float16* hbuf = (_Float16*)big;                  // [E][C][H] fp16, 64 MB
  _Float16* wt   = (_Float16*)(big + 67108864);     // w1t fp16 [E][H][D], 64 MB

  // gating (2048 blocks) + w1 transpose (8192 blocks) co-scheduled
  prep_fused<<<S_TOK / 4 + (HDIM / 64) * (DDIM / 64) * NEXP, 256, 0, stream>>>(
      x, wg, eidx, gtok, w1, wt);
  // per-64-token counts + s2t/rgate init
  scanA<<<128, 64, 0, stream>>>(eidx, cnt, s2t, rgate);
  // prefix (per-block recompute) + ordered scatter
  scanBC<<<128, 64, 0, stream>>>(cnt, eidx, gtok, s2t, rgate, keepf);
  // dispatch (8192 blocks) + dropped-row zeroing (4096 blocks) co-scheduled
  dispatch_zero<<<NEXP * CAP + S_TOK / 2, 128, 0, stream>>>(
      x, s2t, disp, keepf, y);

  // GEMM1: disp[C,1024] x wt^T -> relu -> hbuf.  8-phase 256^2: 512 blocks
  ffn_gemm_m<DDIM, HDIM, 1, true><<<512, 512, 0, stream>>>(
      disp, wt, hbuf, nullptr, nullptr, nullptr);

  // GEMM2: hbuf[C,4096] x w2[4096,1024] (fp32 native) -> scatter to y.  256 blocks.
  ffn_gemm_f2<HDIM, DDIM><<<256, 512, 0, stream>>>(
      hbuf, w2, y, s2t, rgate);
}

// Round 24
// 249.400 us; speedup vs baseline: 1.0305x; 1.0305x over previous
//
#include <hip/hip_runtime.h>
#include <hip/hip_fp16.h>

#define S_TOK 8192
#define DDIM  1024
#define HDIM  4096
#define NEXP  8
#define CAP   1024

typedef __attribute__((ext_vector_type(8))) _Float16 half8;
typedef __attribute__((ext_vector_type(4))) float f32x4;
typedef __attribute__((ext_vector_type(16))) float f32x16;

__device__ __forceinline__ void load_lds16(const _Float16* g, _Float16* l) {
  __builtin_amdgcn_global_load_lds(
      (const __attribute__((address_space(1))) unsigned int*)g,
      (__attribute__((address_space(3))) unsigned int*)l, 16, 0, 0);
}

// ---------------- fused prep: gating (blocks 0..2047) + w1 transpose (2048..) ----------------
__global__ __launch_bounds__(256) void prep_fused(const float* __restrict__ x,
                                                  const float* __restrict__ wg,
                                                  int* __restrict__ eidx,
                                                  float* __restrict__ gtok,
                                                  const float* __restrict__ w1,
                                                  _Float16* __restrict__ wt) {
  if (blockIdx.x < S_TOK / 4) {
    const int s = blockIdx.x * 4 + (threadIdx.x >> 6);
    const int lane = threadIdx.x & 63;
    const float* xr = x + (size_t)s * DDIM;
    float acc[NEXP];
#pragma unroll
    for (int e = 0; e < NEXP; ++e) acc[e] = 0.f;
    for (int d = lane; d < DDIM; d += 64) {
      float xv = xr[d];
      const float4* wrow = (const float4*)(wg + (size_t)d * NEXP);
      float4 w0 = wrow[0], w1v = wrow[1];
      acc[0] += xv * w0.x;  acc[1] += xv * w0.y;
      acc[2] += xv * w0.z;  acc[3] += xv * w0.w;
      acc[4] += xv * w1v.x; acc[5] += xv * w1v.y;
      acc[6] += xv * w1v.z; acc[7] += xv * w1v.w;
    }
#pragma unroll
    for (int off = 32; off > 0; off >>= 1) {
#pragma unroll
      for (int e = 0; e < NEXP; ++e) acc[e] += __shfl_down(acc[e], off);
    }
    if (lane == 0) {
      int best = 0; float bv = acc[0];
#pragma unroll
      for (int e = 1; e < NEXP; ++e) if (acc[e] > bv) { bv = acc[e]; best = e; }
      float sum = 0.f;
#pragma unroll
      for (int e = 0; e < NEXP; ++e) sum += expf(acc[e] - bv);
      eidx[s] = best;
      gtok[s] = 1.f / sum;   // exp(best - max) == 1
    }
  } else {
    __shared__ float tile[64][68];
    const int bid = blockIdx.x - S_TOK / 4;
    const int bx = bid & 63;            // HDIM/64 = 64
    const int by = (bid >> 6) & 15;     // DDIM/64 = 16
    const int bz = bid >> 10;           // NEXP = 8
    const size_t mat = (size_t)DDIM * HDIM;
    const float* ip = w1 + (size_t)bz * mat;
    _Float16* op = wt + (size_t)bz * mat;
    const int r0 = by * 64, c0 = bx * 64;
    {
      const int rl = threadIdx.x >> 2;
      const int cb = (threadIdx.x & 3) * 16;
      const float* src = ip + (size_t)(r0 + rl) * HDIM + c0 + cb;
#pragma unroll
      for (int k = 0; k < 4; ++k) {
        float4 v = *(const float4*)(src + 4 * k);
        tile[rl][cb + 4 * k + 0] = v.x;
        tile[rl][cb + 4 * k + 1] = v.y;
        tile[rl][cb + 4 * k + 2] = v.z;
        tile[rl][cb + 4 * k + 3] = v.w;
      }
    }
    __syncthreads();
    const int cl = threadIdx.x >> 3;
    const int rch = (threadIdx.x & 7) * 8;
#pragma unroll
    for (int pass = 0; pass < 2; ++pass) {
      int cc = cl + pass * 32;
      half8 v;
#pragma unroll
      for (int i = 0; i < 8; ++i) v[i] = (_Float16)tile[rch + i][cc];
      *(half8*)(op + (size_t)(c0 + cc) * DDIM + r0 + rch) = v;
    }
  }
}

// ---------------- hierarchical ordered slot assignment ----------------
__global__ __launch_bounds__(64) void scanA(const int* __restrict__ eidx,
                                            int* __restrict__ cnt) {
  const int blk = blockIdx.x;        // 128 blocks x 64 tokens
  const int lane = threadIdx.x;
  int e = eidx[blk * 64 + lane];
#pragma unroll
  for (int w = 0; w < NEXP; ++w) {
    unsigned long long m = __ballot(e == w);
    if (lane == 0) cnt[blk * NEXP + w] = __popcll(m);
  }
}

// 8 waves, wave w = expert w; also initializes s2t/rgate (runs before scanC)
__global__ __launch_bounds__(512) void scanB(const int* __restrict__ cnt,
                                             int* __restrict__ off,
                                             int* __restrict__ s2t,
                                             float* __restrict__ rgate) {
  const int tid = threadIdx.x;
  for (int i = tid; i < NEXP * CAP; i += 512) { s2t[i] = -1; rgate[i] = 0.f; }
  const int w = tid >> 6;
  const int l = tid & 63;
  int c0 = cnt[(2 * l) * NEXP + w];
  int c1 = cnt[(2 * l + 1) * NEXP + w];
  int s = c0 + c1;
  int run = s;
#pragma unroll
  for (int d = 1; d < 64; d <<= 1) {
    int up = __shfl_up(run, d);
    if (l >= d) run += up;
  }
  int excl = run - s;
  off[(2 * l) * NEXP + w] = excl;
  off[(2 * l + 1) * NEXP + w] = excl + c0;
}

__global__ __launch_bounds__(64) void scanC(const int* __restrict__ eidx,
                                            const float* __restrict__ gtok,
                                            const int* __restrict__ off,
                                            int* __restrict__ s2t,
                                            float* __restrict__ rgate,
                                            int* __restrict__ keepf) {
  const int blk = blockIdx.x;
  const int lane = threadIdx.x;
  const int tok = blk * 64 + lane;
  int e = eidx[tok];
  float g = gtok[tok];
  const unsigned long long below = (1ull << lane) - 1ull;
#pragma unroll
  for (int w = 0; w < NEXP; ++w) {
    unsigned long long m = __ballot(e == w);
    if (e == w) {
      int slot = off[blk * NEXP + w] + __popcll(m & below);
      if (slot < CAP) { s2t[w * CAP + slot] = tok; rgate[w * CAP + slot] = g; }
      keepf[tok] = (slot < CAP) ? 1 : 0;   // every token written exactly once
    }
  }
}

// ---------------- fused dispatch (blocks 0..8191) + zero-dropped (8192..) ----------------
__global__ __launch_bounds__(128) void dispatch_zero(const float* __restrict__ x,
                                                     const int* __restrict__ s2t,
                                                     _Float16* __restrict__ disp,
                                                     const int* __restrict__ keepf,
                                                     float* __restrict__ y) {
  if (blockIdx.x < NEXP * CAP) {
    const int row = blockIdx.x;
    const int t = threadIdx.x;
    const int token = s2t[row];
    half8 v;
    if (token >= 0) {
      const float4* xr = (const float4*)(x + (size_t)token * DDIM);
      float4 a = xr[2 * t], b = xr[2 * t + 1];
      v[0] = (_Float16)a.x; v[1] = (_Float16)a.y; v[2] = (_Float16)a.z; v[3] = (_Float16)a.w;
      v[4] = (_Float16)b.x; v[5] = (_Float16)b.y; v[6] = (_Float16)b.z; v[7] = (_Float16)b.w;
    } else {
#pragma unroll
      for (int i = 0; i < 8; ++i) v[i] = (_Float16)0.f;
    }
    *(half8*)(disp + (size_t)row * DDIM + t * 8) = v;
  } else {
    const int tok = (blockIdx.x - NEXP * CAP) * 2 + (threadIdx.x >> 6);
    if (keepf[tok]) return;
    const int lane = threadIdx.x & 63;
    float4* yr = (float4*)(y + (size_t)tok * DDIM);
#pragma unroll
    for (int i = 0; i < 4; ++i) yr[lane + i * 64] = {0.f, 0.f, 0.f, 0.f};
  }
}

// ---------------- GEMM1: m201 8-phase template (r8/r16-proven, ~93 us) ----------------
template <int KDIM, int NDIM, int SPLITK, bool FIRST>
__global__ __launch_bounds__(512, 2) void ffn_gemm_m(const _Float16* __restrict__ A_set,
                                                     const _Float16* __restrict__ B_set,
                                                     _Float16* __restrict__ Hout,
                                                     float* __restrict__ Y,
                                                     const int* __restrict__ s2t,
                                                     const float* __restrict__ rgate) {
  __shared__ __align__(16) _Float16 As[4 * 8192];   // [d*2+h][128][64]
  __shared__ __align__(16) _Float16 Bs[4 * 8192];
  constexpr int TILES = 4 * (NDIM / 256);
  constexpr int PER_E = TILES * SPLITK;
  constexpr int NTSEG = KDIM / 64 / SPLITK;
  constexpr int NI = NTSEG / 2;
  const int wg = blockIdx.x;
  const int swz = (wg & 7) * PER_E + (wg >> 3);   // bijective; xcd == expert
  const int z = swz / PER_E;
  const int s2 = swz % PER_E;
  const int tile = s2 % TILES;
  const int kseg = s2 / TILES;
  const int m0 = (tile & 3) * 256;
  const int n0 = (tile >> 2) * 256;
  const int kt0 = kseg * NTSEG;

  const int tid = threadIdx.x;
  const _Float16* Ae = A_set + (size_t)z * 1024 * KDIM;
  const _Float16* Be = B_set + (size_t)z * (size_t)NDIM * KDIM;

  const int sr0 = tid >> 3;
  const int sc0 = tid & 7;
  auto STG = [&](const _Float16* gbase, _Float16* lbase, int rowbase, int kt) {
#pragma unroll
    for (int j = 0; j < 2; ++j) {
      int r = j * 64 + sr0;
      load_lds16(gbase + (size_t)(rowbase + r) * KDIM + kt * 64 + ((sc0 ^ (r & 7)) << 3),
                 lbase + j * 4096 + tid * 8);
    }
  };

  const int lane = tid & 63, wid = tid >> 6;
  const int fr = lane & 15, fq = lane >> 4;
  const int war = (wid >> 2) * 64;
  const int wbr = (wid & 3) * 32;
  int offA[4][2], offB[2][2];
#pragma unroll
  for (int m = 0; m < 4; ++m)
#pragma unroll
    for (int ks = 0; ks < 2; ++ks) {
      int r = war + m * 16 + fr, c = ks * 4 + fq;
      offA[m][ks] = r * 64 + ((c ^ (r & 7)) << 3);
    }
#pragma unroll
  for (int n = 0; n < 2; ++n)
#pragma unroll
    for (int ks = 0; ks < 2; ++ks) {
      int r = wbr + n * 16 + fr, c = ks * 4 + fq;
      offB[n][ks] = r * 64 + ((c ^ (r & 7)) << 3);
    }

  f32x4 acc[4][4][2];
#pragma unroll
  for (int q = 0; q < 4; ++q)
#pragma unroll
    for (int m = 0; m < 4; ++m)
#pragma unroll
      for (int n = 0; n < 2; ++n) acc[q][m][n] = {0.f, 0.f, 0.f, 0.f};

#define BAR __builtin_amdgcn_s_barrier()
#define PUBFENCE __builtin_amdgcn_sched_barrier(0)
#define RDA(KK, MH) { _Pragma("unroll") for (int m = 0; m < 4; ++m) { \
      af[m][0] = *(const half8*)(As + ((KK) * 2 + (MH)) * 8192 + offA[m][0]); \
      af[m][1] = *(const half8*)(As + ((KK) * 2 + (MH)) * 8192 + offA[m][1]); } }
#define RDB(KK, NH, BF) { _Pragma("unroll") for (int n = 0; n < 2; ++n) { \
      BF[n][0] = *(const half8*)(Bs + ((KK) * 2 + (NH)) * 8192 + offB[n][0]); \
      BF[n][1] = *(const half8*)(Bs + ((KK) * 2 + (NH)) * 8192 + offB[n][1]); } }
#define MM16(Q, BF) { __builtin_amdgcn_s_setprio(1); \
    _Pragma("unroll") for (int ks = 0; ks < 2; ++ks) \
    _Pragma("unroll") for (int m = 0; m < 4; ++m) \
    _Pragma("unroll") for (int n = 0; n < 2; ++n) \
      acc[Q][m][n] = __builtin_amdgcn_mfma_f32_16x16x32_f16(af[m][ks], BF[n][ks], acc[Q][m][n], 0, 0, 0); \
    __builtin_amdgcn_s_setprio(0); }

  STG(Ae, As + 0 * 8192, m0 + 0,   kt0);
  STG(Be, Bs + 0 * 8192, n0 + 0,   kt0);
  STG(Ae, As + 1 * 8192, m0 + 128, kt0);
  STG(Be, Bs + 1 * 8192, n0 + 128, kt0);
  STG(Ae, As + 2 * 8192, m0 + 0,   kt0 + 1);
  STG(Be, Bs + 2 * 8192, n0 + 0,   kt0 + 1);
  asm volatile("s_waitcnt vmcnt(4)" ::: "memory");
  PUBFENCE;
  BAR;

#pragma unroll 1
  for (int i = 0; i < NI; ++i) {
    const int ka = kt0 + 2 * i;
    const bool more = (i + 1 < NI);
    half8 af[4][2], bfA[2][2], bfB[2][2];
    RDA(0, 0); RDB(0, 0, bfA);
    STG(Ae, As + 3 * 8192, m0 + 128, ka + 1);
    BAR; MM16(0, bfA); BAR;
    RDB(0, 1, bfB);
    STG(Be, Bs + 3 * 8192, n0 + 128, ka + 1);
    BAR; MM16(1, bfB); BAR;
    RDA(0, 1);
    if (more) STG(Ae, As + 0 * 8192, m0 + 0, ka + 2);
    BAR; MM16(2, bfA); BAR;
    if (more) {
      STG(Be, Bs + 0 * 8192, n0 + 0, ka + 2);
      asm volatile("s_waitcnt vmcnt(4)" ::: "memory");
    } else {
      asm volatile("s_waitcnt vmcnt(0)" ::: "memory");
    }
    PUBFENCE;
    BAR; MM16(3, bfB); BAR;
    RDA(1, 0); RDB(1, 0, bfA);
    if (more) STG(Ae, As + 1 * 8192, m0 + 128, ka + 2);
    BAR; MM16(0, bfA); BAR;
    RDB(1, 1, bfB);
    if (more) STG(Be, Bs + 1 * 8192, n0 + 128, ka + 2);
    BAR; MM16(1, bfB); BAR;
    RDA(1, 1);
    if (more) STG(Ae, As + 2 * 8192, m0 + 0, ka + 3);
    BAR; MM16(2, bfA); BAR;
    if (more) {
      STG(Be, Bs + 2 * 8192, n0 + 0, ka + 3);
      asm volatile("s_waitcnt vmcnt(4)" ::: "memory");
      PUBFENCE;
    }
    BAR; MM16(3, bfB); BAR;
  }
#undef MM16
#undef RDB
#undef RDA
#undef PUBFENCE
#undef BAR

#pragma unroll
  for (int q = 0; q < 4; ++q) {
    const int mh = q >> 1, nh = q & 1;
#pragma unroll
    for (int m = 0; m < 4; ++m) {
      const int rowb = m0 + mh * 128 + war + m * 16 + fq * 4;
      const int colb = n0 + nh * 128 + wbr + fr;
      if (FIRST) {
#pragma unroll
        for (int j = 0; j < 4; ++j) {
          size_t row = (size_t)z * 1024 + rowb + j;
#pragma unroll
          for (int n = 0; n < 2; ++n)
            Hout[row * (size_t)NDIM + colb + n * 16] = (_Float16)fmaxf(acc[q][m][n][j], 0.f);
        }
      } else {
        const int srow = z * CAP + rowb;
#pragma unroll
        for (int j = 0; j < 4; ++j) {
          int token = s2t[srow + j];
          if (token < 0) continue;
          float g = rgate[srow + j];
#pragma unroll
          for (int n = 0; n < 2; ++n) {
            if (SPLITK > 1)
              atomicAdd(&Y[(size_t)token * DDIM + colb + n * 16], acc[q][m][n][j] * g);
            else
              Y[(size_t)token * DDIM + colb + n * 16] = acc[q][m][n][j] * g;
          }
        }
      }
    }
  }
}

// ---------------- GEMM2 "fused-B v5.2" (r21-proven, ~117 us) ----------------
template <int KDIM, int NDIM>
__global__ __launch_bounds__(512, 1) void ffn_gemm_f2(const _Float16* __restrict__ A_set,
                                                      const float* __restrict__ B_set,
                                                      float* __restrict__ Y,
                                                      const int* __restrict__ s2t,
                                                      const float* __restrict__ rgate) {
  __shared__ __align__(16) _Float16 As[2 * 16384];  // [buf][256 rows][64 k]
  __shared__ __align__(16) _Float16 Bs[2 * 8192];   // [buf][128 n][64 k]
  constexpr int NT = KDIM / 64;
  constexpr int TILES = (NDIM / 128) * 4;
  const int wg = blockIdx.x;
  const int swz = (wg & 7) * TILES + (wg >> 3);
  const int z = swz / TILES;
  const int s2 = swz % TILES;
  const int xx = s2 >> 2;
  const int yy = s2 & 3;
  const int m0 = yy * 256, n0 = xx * 128;

  const int tid = threadIdx.x;
  const _Float16* Ae = A_set + (size_t)z * 1024 * KDIM;
  const float* Be = B_set + (size_t)z * (size_t)KDIM * NDIM;

  const int sr = tid >> 3;
  const int sc = tid & 7;
  auto STAGE_A = [&](int buf, int kt) {
#pragma unroll
    for (int j = 0; j < 4; ++j) {
      int r = j * 64 + sr;
      load_lds16(Ae + (size_t)(m0 + r) * KDIM + kt * 64 + ((sc ^ (r & 7)) << 3),
                 As + buf * 16384 + j * 4096 + tid * 8);
    }
  };

  const int bq = tid & 31;
  const int bkb = ((tid >> 5) & 7) * 8;
  auto LOAD_B = [&](float4* br, int kt) {
#pragma unroll
    for (int i = 0; i < 8; ++i)
      br[i] = *(const float4*)(Be + (size_t)(kt * 64 + bkb + i) * NDIM + n0 + 4 * bq);
  };
  auto WRITE_B = [&](const float4* br, int buf) {
    _Float16* Bb = Bs + buf * 8192;
#pragma unroll
    for (int w = 0; w < 4; ++w) {
      int n = 4 * bq + w;
      half8 h;
#pragma unroll
      for (int i = 0; i < 8; ++i) h[i] = (_Float16)br[i][w];
      int c = (bkb >> 3) ^ (((n >> 2) ^ n) & 7);
      *(half8*)(Bb + n * 64 + c * 8) = h;
    }
  };

  const int lane = tid & 63, wid = tid >> 6;
  const bool bstage = (wid < 4);
  const int wr = (wid >> 1) * 64;
  const int wc = (wid & 1) * 64;
  const int r32 = lane & 31;
  const int khalf = lane >> 5;
  int offA[2][4], offB[2][4];
#pragma unroll
  for (int t2 = 0; t2 < 2; ++t2)
#pragma unroll
    for (int kf = 0; kf < 4; ++kf) {
      int ra = wr + t2 * 32 + r32, c = kf * 2 + khalf;
      offA[t2][kf] = ra * 64 + ((c ^ (ra & 7)) << 3);
      int nb = wc + t2 * 32 + r32;
      offB[t2][kf] = nb * 64 + ((c ^ (((nb >> 2) ^ nb) & 7)) << 3);
    }

  f32x16 acc[2][2];
#pragma unroll
  for (int m = 0; m < 2; ++m)
#pragma unroll
    for (int n = 0; n < 2; ++n)
#pragma unroll
      for (int j = 0; j < 16; ++j) acc[m][n][j] = 0.f;

  auto COMPUTE = [&](int buf) {
    const _Float16* Ab = As + buf * 16384;
    const _Float16* Bb = Bs + buf * 8192;
    __builtin_amdgcn_s_setprio(1);
#pragma unroll
    for (int kf = 0; kf < 4; ++kf) {
      half8 a0 = *(const half8*)(Ab + offA[0][kf]);
      half8 a1 = *(const half8*)(Ab + offA[1][kf]);
      half8 b0 = *(const half8*)(Bb + offB[0][kf]);
      half8 b1 = *(const half8*)(Bb + offB[1][kf]);
      acc[0][0] = __builtin_amdgcn_mfma_f32_32x32x16_f16(a0, b0, acc[0][0], 0, 0, 0);
      acc[0][1] = __builtin_amdgcn_mfma_f32_32x32x16_f16(a0, b1, acc[0][1], 0, 0, 0);
      acc[1][0] = __builtin_amdgcn_mfma_f32_32x32x16_f16(a1, b0, acc[1][0], 0, 0, 0);
      acc[1][1] = __builtin_amdgcn_mfma_f32_32x32x16_f16(a1, b1, acc[1][1], 0, 0, 0);
    }
    __builtin_amdgcn_s_setprio(0);
  };

#define BARRIER8 do { \
    if (bstage) asm volatile("s_waitcnt vmcnt(8) lgkmcnt(0)" ::: "memory"); \
    else        asm volatile("s_waitcnt vmcnt(0) lgkmcnt(0)" ::: "memory"); \
    __builtin_amdgcn_sched_barrier(0); \
    __builtin_amdgcn_s_barrier(); \
    __builtin_amdgcn_sched_barrier(0); } while (0)

  float4 bregA[8], bregB[8];
  if (bstage) LOAD_B(bregA, 0);
  STAGE_A(0, 0);
  if (bstage) {
    WRITE_B(bregA, 0);
    LOAD_B(bregB, 1 & (NT - 1));
  }
  BARRIER8;

#pragma unroll 1
  for (int i = 0; i < NT; i += 2) {
    STAGE_A(1, (i + 1) & (NT - 1));
    if (bstage) {
      LOAD_B(bregA, (i + 2) & (NT - 1));
      WRITE_B(bregB, 1);          // cvt+ds_write overlap the MFMA cluster below
    }
    COMPUTE(0);
    BARRIER8;
    if (i + 2 < NT) STAGE_A(0, (i + 2) & (NT - 1));
    if (bstage) {
      LOAD_B(bregB, (i + 3) & (NT - 1));
      if (i + 2 < NT) WRITE_B(bregA, 0);
    }
    COMPUTE(1);
    BARRIER8;
  }
#undef BARRIER8

#pragma unroll
  for (int mt = 0; mt < 2; ++mt) {
#pragma unroll
    for (int nt = 0; nt < 2; ++nt) {
      const int gcol = n0 + wc + nt * 32 + r32;
#pragma unroll
      for (int reg = 0; reg < 16; ++reg) {
        const int rowf = (reg & 3) + 8 * (reg >> 2) + 4 * khalf;
        const int grow = m0 + wr + mt * 32 + rowf;
        int token = s2t[z * CAP + grow];
        if (token >= 0) {
          float g = rgate[z * CAP + grow];
          Y[(size_t)token * DDIM + gcol] = acc[mt][nt][reg] * g;
        }
      }
    }
  }
}

extern "C" void kernel_launch(void* const* d_in, const int* in_sizes, int n_in,
                              void* d_out, int out_size, void* d_ws, size_t ws_size,
                              hipStream_t stream) {
  const float* x  = (const float*)d_in[0];
  const float* wg = (const float*)d_in[1];
  const float* w1 = (const float*)d_in[2];
  const float* w2 = (const float*)d_in[3];
  float* y = (float*)d_out;

  char* ws = (char*)d_ws;
  int*   eidx  = (int*)(ws);                 // 32 KB
  float* gtok  = (float*)(ws + 32768);       // 32 KB
  int*   s2t   = (int*)(ws + 65536);         // 32 KB
  float* rgate = (float*)(ws + 98304);       // 32 KB
  int*   cnt   = (int*)(ws + 131072);        // 4 KB
  int*   off   = (int*)(ws + 135168);        // 4 KB
  int*   keepf = (int*)(ws + 139264);        // 32 KB
  _Float16* disp = (_Float16*)(ws + 180224); // 16 MB
  char* big = ws + 180224 + (size_t)NEXP * CAP * DDIM * 2;
  _Float16* hbuf = (_Float16*)big;                  // [E][C][H] fp16, 64 MB
  _Float16* wt   = (_Float16*)(big + 67108864);     // w1t fp16 [E][H][D], 64 MB

  // gating (2048 blocks) + w1 transpose (8192 blocks) co-scheduled
  prep_fused<<<S_TOK / 4 + (HDIM / 64) * (DDIM / 64) * NEXP, 256, 0, stream>>>(
      x, wg, eidx, gtok, w1, wt);
  scanA<<<128, 64, 0, stream>>>(eidx, cnt);
  scanB<<<1, 512, 0, stream>>>(cnt, off, s2t, rgate);
  scanC<<<128, 64, 0, stream>>>(eidx, gtok, off, s2t, rgate, keepf);
  // dispatch (8192 blocks) + dropped-row zeroing (4096 blocks) co-scheduled
  dispatch_zero<<<NEXP * CAP + S_TOK / 2, 128, 0, stream>>>(
      x, s2t, disp, keepf, y);

  // GEMM1: disp[C,1024] x wt^T -> relu -> hbuf.  8-phase 256^2: 512 blocks
  ffn_gemm_m<DDIM, HDIM, 1, true><<<512, 512, 0, stream>>>(
      disp, wt, hbuf, nullptr, nullptr, nullptr);

  // GEMM2: hbuf[C,4096] x w2[4096,1024] (fp32 native) -> scatter to y.  256 blocks.
  ffn_gemm_f2<HDIM, DDIM><<<256, 512, 0, stream>>>(
      hbuf, w2, y, s2t, rgate);
}